// Round 14
// baseline (27.308 us; speedup 1.0000x reference)
//
#include <hip/hip_runtime.h>
#include <cmath>

// Problem constants: B=4, L=8192, H=128, P=64
constexpr int Bn = 4;
constexpr int Ln = 8192;
constexpr int Hn = 128;
constexpr int Pn = 64;
constexpr int Kn = 128;         // 2*P interleaved (k = 2p+c)
constexpr int Sc = 64;          // chunk length (rows per block)
constexpr int NC = Ln / Sc;     // 128 chunks per batch
constexpr int NBLK = Bn * NC;   // 512 blocks

typedef float f4 __attribute__((ext_vector_type(4)));
typedef float f32x4 __attribute__((ext_vector_type(4)));
typedef unsigned short us8 __attribute__((ext_vector_type(8)));
typedef unsigned short us4 __attribute__((ext_vector_type(4)));
typedef __bf16 bf16x8 __attribute__((ext_vector_type(8)));

__device__ __forceinline__ unsigned short f2bf(float f) {
  unsigned u = __builtin_bit_cast(unsigned, f);
  u += 0x7fffu + ((u >> 16) & 1u);        // round-to-nearest-even
  return (unsigned short)(u >> 16);
}
__device__ __forceinline__ float bf2f(unsigned short v) {
  return __builtin_bit_cast(float, (unsigned)v << 16);
}

__device__ __forceinline__ f32x4 mfma_bf16(us8 a, us8 b, f32x4 c) {
  return __builtin_amdgcn_mfma_f32_16x16x32_bf16(
      __builtin_bit_cast(bf16x8, a), __builtin_bit_cast(bf16x8, b), c, 0, 0, 0);
}

__device__ __forceinline__ void make_M(float A, float st,
    float& m11, float& m12, float& m21, float& m22) {
  float s2A   = st * st * A;
  float schur = 1.0f / (1.0f + s2A);
  m11 = 1.0f - s2A * schur;
  m12 = -st * A * schur;
  m21 = st * schur;
  m22 = schur;
}

struct M22 { float a, b, c, d; };   // [[a,b],[c,d]]
__device__ __forceinline__ M22 mmul(M22 X, M22 Y) {
  return { X.a * Y.a + X.b * Y.c, X.a * Y.b + X.b * Y.d,
           X.c * Y.a + X.d * Y.c, X.c * Y.b + X.d * Y.d };
}

// W-in-LDS swizzle: row n (256B), byte ^= (n&7)<<4  (read & write use same involution)
__device__ __forceinline__ char* wswz(unsigned short* wlds, int n, int byteInRow) {
  return (char*)wlds + ((n * 256 + byteInRow) ^ ((n & 7) << 4));
}
__device__ __forceinline__ const char* wswz_c(const unsigned short* wlds, int n, int byteInRow) {
  return (const char*)wlds + ((n * 256 + byteInRow) ^ ((n & 7) << 4));
}

// ------------------------------------------------- K1: Wb->LDS + GEMM1(reg) + zero-init scan -> ysl + carry
__global__ __launch_bounds__(256) void k1_kernel(
    const float* __restrict__ u, const float* __restrict__ Br,
    const float* __restrict__ Bi, const float* __restrict__ Ad,
    const float* __restrict__ steps,
    float2* __restrict__ carry, unsigned short* __restrict__ ysl) {
  __shared__ unsigned short usb[Sc * Hn];   // 16 KB: u-tile (swz), later ys_local bf16 (linear)
  __shared__ float bu[Sc * Kn];             // 32 KB: first Wb bf16 (swz), then Bu f32
  unsigned short* wlds = (unsigned short*)bu;
  const int t = threadIdx.x;
  const int b = blockIdx.x >> 7;            // NC = 128
  const int chunk = blockIdx.x & (NC - 1);
  const size_t row0 = (size_t)b * Ln + (size_t)chunk * Sc;

  // stage u tile -> bf16 swizzled LDS
  const f4* __restrict__ u4 = (const f4*)(u + row0 * Hn);
  #pragma unroll
  for (int i = 0; i < 8; ++i) {
    int idx = t + i * 256;
    f4 v = u4[idx];
    int row = idx >> 5, c0 = (idx & 31) * 4;
    us4 pk = {f2bf(v[0]), f2bf(v[1]), f2bf(v[2]), f2bf(v[3])};
    *(us4*)((char*)usb + ((row * 256 + c0 * 2) ^ ((row & 7) << 4))) = pk;
  }

  // stage Wb -> LDS bf16 (swizzled): WbN[n][h] = (n&1?Bi:Br)[n>>1][h]
  #pragma unroll
  for (int i = 0; i < 16; ++i) {
    int idx4 = t + i * 256;                 // 0..4095 us4-groups
    int n = idx4 >> 5, h4 = idx4 & 31;      // h = 4*h4
    const float* __restrict__ src = ((n & 1) ? Bi : Br) + (n >> 1) * Hn + h4 * 4;
    f4 w = *(const f4*)src;
    us4 pk = {f2bf(w[0]), f2bf(w[1]), f2bf(w[2]), f2bf(w[3])};
    *(us4*)wswz(wlds, n, h4 * 8) = pk;
  }
  __syncthreads();

  // GEMM1, all 8 col-tiles accumulated in registers
  const int wave = t >> 6, lane = t & 63;
  const int arow = wave * 16 + (lane & 15);
  const int kg = lane >> 4;                 // h = kk*32 + kg*8 + j

  us8 afr[4];
  #pragma unroll
  for (int kk = 0; kk < 4; ++kk)
    afr[kk] = *(const us8*)((const char*)usb +
        ((arow * 256 + kk * 64 + kg * 16) ^ ((arow & 7) << 4)));

  f32x4 accs[8];
  #pragma unroll
  for (int nt = 0; nt < 8; ++nt) {
    const int n = nt * 16 + (lane & 15);
    f32x4 acc = {0.f, 0.f, 0.f, 0.f};
    #pragma unroll
    for (int kk = 0; kk < 4; ++kk) {
      us8 bfr = *(const us8*)wswz_c(wlds, n, kk * 64 + kg * 16);
      acc = mfma_bf16(afr[kk], bfr, acc);
    }
    accs[nt] = acc;
  }
  __syncthreads();          // all W reads complete before clobbering with Bu

  const int crow = wave * 16 + (lane >> 4) * 4;   // verified m89 C/D mapping
  #pragma unroll
  for (int nt = 0; nt < 8; ++nt) {
    const int ccol = nt * 16 + (lane & 15);
    #pragma unroll
    for (int r = 0; r < 4; ++r)
      bu[(crow + r) * Kn + ccol] = accs[nt][r];
  }
  __syncthreads();

  // local zero-init scan; ys_local(x) -> usb (linear bf16), carry -> global
  if (t < Kn) {
    const int p = t >> 1;
    const float A  = fmaxf(Ad[p], 0.0f);
    const float st = 1.0f / (1.0f + expf(-steps[p]));
    float m11, m12, m21, m22;
    make_M(A, st, m11, m12, m21, m22);
    const float f1 = m11 * st, f2 = m21 * st;
    float z = 0.f, x = 0.f;
    #pragma unroll 8
    for (int s = 0; s < Sc; ++s) {
      float bv = bu[s * Kn + t];
      float zn = fmaf(m11, z, fmaf(m12, x, f1 * bv));
      float xn = fmaf(m21, z, fmaf(m22, x, f2 * bv));
      z = zn; x = xn;
      usb[s * Kn + t] = f2bf(x);
    }
    carry[((size_t)b * NC + chunk) * Kn + t] = make_float2(z, x);
  }
  __syncthreads();

  // ys_local bf16 tile -> global (vectorized, coalesced)
  const us8* src = (const us8*)usb;
  us8* dst = (us8*)(ysl + row0 * Kn);
  #pragma unroll
  for (int i = 0; i < 4; ++i) dst[t + i * 256] = src[t + i * 256];
}

// ------------------------------------------------- K2: wave-parallel carry propagation (proven r8)
__global__ __launch_bounds__(256) void k2_propagate(
    const float* __restrict__ Ad, const float* __restrict__ steps,
    float2* __restrict__ carry) {
  const int wave = threadIdx.x >> 6, lane = threadIdx.x & 63;
  const int series = blockIdx.x * 4 + wave;   // 0..511
  const int sb = series >> 7;
  const int k = series & 127;
  const int p = k >> 1;

  const float A  = fmaxf(Ad[p], 0.0f);
  const float st = 1.0f / (1.0f + expf(-steps[p]));
  float m11, m12, m21, m22;
  make_M(A, st, m11, m12, m21, m22);
  // Mc = M^Sc (Sc=64 -> 6 squarings)
  float ca = m11, cb = m12, cc = m21, cd = m22;
  #pragma unroll
  for (int i = 0; i < 6; ++i) {
    float na = ca * ca + cb * cc;
    float nb = ca * cb + cb * cd;
    float nc = cc * ca + cd * cc;
    float nd = cc * cb + cd * cd;
    ca = na; cb = nb; cc = nc; cd = nd;
  }

  const size_t base = (size_t)sb * NC * Kn + k;
  float2 c0 = carry[base + (size_t)(2 * lane) * Kn];
  float2 c1 = carry[base + (size_t)(2 * lane + 1) * Kn];

  // lane-local fold of chunks {2i, 2i+1}
  float Aa = ca * ca + cb * cc;
  float Ab = ca * cb + cb * cd;
  float Ac = cc * ca + cd * cc;
  float Adl = cc * cb + cd * cd;
  float bz = ca * c0.x + cb * c0.y + c1.x;
  float bx = cc * c0.x + cd * c0.y + c1.y;

  // inclusive shfl-scan of affine maps
  #pragma unroll
  for (int d = 1; d < 64; d <<= 1) {
    float oAa = __shfl_up(Aa, d), oAb = __shfl_up(Ab, d);
    float oAc = __shfl_up(Ac, d), oAd = __shfl_up(Adl, d);
    float obz = __shfl_up(bz, d), obx = __shfl_up(bx, d);
    if (lane >= d) {
      float nbz = Aa * obz + Ab * obx + bz;
      float nbx = Ac * obz + Adl * obx + bx;
      float nAa = Aa * oAa + Ab * oAc;
      float nAb = Aa * oAb + Ab * oAd;
      float nAc = Ac * oAa + Adl * oAc;
      float nAd = Ac * oAb + Adl * oAd;
      Aa = nAa; Ab = nAb; Ac = nAc; Adl = nAd; bz = nbz; bx = nbx;
    }
  }

  // exclusive prefix; init for chunk 2i, then 2i+1 = Mc*init + c0
  float ebz = __shfl_up(bz, 1);
  float ebx = __shfl_up(bx, 1);
  if (lane == 0) { ebz = 0.f; ebx = 0.f; }

  carry[base + (size_t)(2 * lane) * Kn]     = make_float2(ebz, ebx);
  carry[base + (size_t)(2 * lane + 1) * Kn] =
      make_float2(ca * ebz + cb * ebx + c0.x, cc * ebz + cd * ebx + c0.y);
}

// ------------------------------------------------- K3: u-prefetch + Wc->LDS + correction + GEMM2(reg) + residual
__global__ __launch_bounds__(256) void k3_kernel(
    const float* __restrict__ u, const float* __restrict__ Cr,
    const float* __restrict__ Ci, const float* __restrict__ Dv,
    const float* __restrict__ Ad, const float* __restrict__ steps,
    const float2* __restrict__ carry, const unsigned short* __restrict__ ysl,
    float* __restrict__ out) {
  __shared__ unsigned short usb[Sc * Kn];   // 16 KB: corrected ys bf16 (swizzled)
  __shared__ float olds[Sc * Kn];           // 32 KB: first Wc bf16 (swz), then GEMM2 output
  unsigned short* wlds = (unsigned short*)olds;
  const int t = threadIdx.x;
  const int b = blockIdx.x >> 7;
  const int chunk = blockIdx.x & (NC - 1);
  const size_t row0 = (size_t)b * Ln + (size_t)chunk * Sc;

  // T14: issue the residual's u loads NOW; latency hides under ladder + GEMM2
  const f4* __restrict__ u4 = (const f4*)(u + row0 * Hn);
  f4 ureg[8];
  #pragma unroll
  for (int i = 0; i < 8; ++i) ureg[i] = u4[t + i * 256];

  // stage Wc -> LDS bf16 (swizzled): WcH[h][k] = (k&1 ? -Ci : Cr)[h][k>>1]
  #pragma unroll
  for (int i = 0; i < 16; ++i) {
    int idx4 = t + i * 256;                 // 0..4095 us4-groups
    int h = idx4 >> 5, k4 = (idx4 & 31) * 4;
    const float2 cr = *(const float2*)(Cr + h * Pn + (k4 >> 1));
    const float2 ci = *(const float2*)(Ci + h * Pn + (k4 >> 1));
    us4 pk = {f2bf(cr.x), f2bf(-ci.x), f2bf(cr.y), f2bf(-ci.y)};
    *(us4*)wswz(wlds, h, k4 * 2) = pk;
  }

  const int tc = t & 31;        // cols k = 4tc..4tc+3; p = {2tc, 2tc+1}
  const int r0 = t >> 5;        // rows r0, r0+8, ..., r0+56

  // chunk init state per k (fixed per thread)
  const size_t cbase = ((size_t)b * NC + chunk) * Kn;
  float2 iv[4];
  #pragma unroll
  for (int j = 0; j < 4; ++j) iv[j] = carry[cbase + 4 * tc + j];

  // per-p transition matrices and power ladder: row s needs M^(s+1)
  M22 M0, M1;
  {
    int p0 = 2 * tc, p1 = 2 * tc + 1;
    float A0 = fmaxf(Ad[p0], 0.0f), A1 = fmaxf(Ad[p1], 0.0f);
    float s0 = 1.0f / (1.0f + expf(-steps[p0]));
    float s1 = 1.0f / (1.0f + expf(-steps[p1]));
    make_M(A0, s0, M0.a, M0.b, M0.c, M0.d);
    make_M(A1, s1, M1.a, M1.b, M1.c, M1.d);
  }
  M22 M8_0 = mmul(mmul(mmul(M0, M0), mmul(M0, M0)), mmul(mmul(M0, M0), mmul(M0, M0)));
  M22 M8_1 = mmul(mmul(mmul(M1, M1), mmul(M1, M1)), mmul(mmul(M1, M1), mmul(M1, M1)));
  M22 R0 = M0, R1 = M1;                    // M^(r0+1)
  for (int q = 0; q < r0; ++q) { R0 = mmul(R0, M0); R1 = mmul(R1, M1); }

  // corrected ys -> bf16 swizzled A-tile
  const unsigned short* yrow = ysl + row0 * Kn + 4 * tc;
  #pragma unroll
  for (int i = 0; i < 8; ++i) {
    const int row = r0 + 8 * i;
    us4 yv = *(const us4*)(yrow + (size_t)row * Kn);
    float y0 = bf2f(yv[0]) + fmaf(R0.c, iv[0].x, R0.d * iv[0].y);
    float y1 = bf2f(yv[1]) + fmaf(R0.c, iv[1].x, R0.d * iv[1].y);
    float y2 = bf2f(yv[2]) + fmaf(R1.c, iv[2].x, R1.d * iv[2].y);
    float y3 = bf2f(yv[3]) + fmaf(R1.c, iv[3].x, R1.d * iv[3].y);
    us4 pk = {f2bf(y0), f2bf(y1), f2bf(y2), f2bf(y3)};
    *(us4*)((char*)usb + ((row * 256 + tc * 8) ^ ((row & 7) << 4))) = pk;
    R0 = mmul(M8_0, R0); R1 = mmul(M8_1, R1);
  }
  __syncthreads();

  // GEMM2, all 8 col-tiles in registers (B-frags from swizzled LDS Wc)
  const int wave = t >> 6, lane = t & 63;
  const int arow = wave * 16 + (lane & 15);
  const int kg = lane >> 4;

  us8 afr[4];
  #pragma unroll
  for (int kk = 0; kk < 4; ++kk)
    afr[kk] = *(const us8*)((const char*)usb +
        ((arow * 256 + kk * 64 + kg * 16) ^ ((arow & 7) << 4)));

  f32x4 accs[8];
  #pragma unroll
  for (int nt = 0; nt < 8; ++nt) {
    const int n = nt * 16 + (lane & 15);   // h
    f32x4 acc = {0.f, 0.f, 0.f, 0.f};
    #pragma unroll
    for (int kk = 0; kk < 4; ++kk) {
      us8 bfr = *(const us8*)wswz_c(wlds, n, kk * 64 + kg * 16);
      acc = mfma_bf16(afr[kk], bfr, acc);
    }
    accs[nt] = acc;
  }
  __syncthreads();          // all W reads complete before clobbering with output

  const int crow = wave * 16 + (lane >> 4) * 4;
  #pragma unroll
  for (int nt = 0; nt < 8; ++nt) {
    const int ccol = nt * 16 + (lane & 15);
    #pragma unroll
    for (int r = 0; r < 4; ++r)
      olds[(crow + r) * Kn + ccol] = accs[nt][r];
  }
  __syncthreads();

  // residual (u from prefetched regs) + coalesced store
  const f4* __restrict__ Dv4 = (const f4*)Dv;
  f4* __restrict__ out4 = (f4*)out;
  #pragma unroll
  for (int i = 0; i < 8; ++i) {
    int idx = t + i * 256;
    int row = idx >> 5, c0 = (idx & 31) * 4;
    f4 acc = *(const f4*)&olds[row * Kn + c0];
    f4 dv = Dv4[idx & 31];
    f4 res;
    #pragma unroll
    for (int j = 0; j < 4; ++j) res[j] = fmaf(ureg[i][j], dv[j], acc[j]);
    out4[row0 * (Hn / 4) + idx] = res;
  }
}

extern "C" void kernel_launch(void* const* d_in, const int* in_sizes, int n_in,
                              void* d_out, int out_size, void* d_ws, size_t ws_size,
                              hipStream_t stream) {
  const float* u     = (const float*)d_in[0];
  const float* Ad    = (const float*)d_in[1];
  const float* Br    = (const float*)d_in[2];
  const float* Bi    = (const float*)d_in[3];
  const float* Cr    = (const float*)d_in[4];
  const float* Ci    = (const float*)d_in[5];
  const float* Dv    = (const float*)d_in[6];
  const float* steps = (const float*)d_in[7];
  float* out = (float*)d_out;

  // ws: carry [B*NC*Kn float2 = 512KB] | ysl bf16 [8MB]
  float2* carry = (float2*)d_ws;
  unsigned short* ysl = (unsigned short*)(carry + (size_t)Bn * NC * Kn);

  k1_kernel   <<<NBLK,        256, 0, stream>>>(u, Br, Bi, Ad, steps, carry, ysl);
  k2_propagate<<<Bn * Kn / 4, 256, 0, stream>>>(Ad, steps, carry);
  k3_kernel   <<<NBLK,        256, 0, stream>>>(u, Cr, Ci, Dv, Ad, steps, carry, ysl, out);
}

// Round 15
// 26.285 us; speedup vs baseline: 1.0389x; 1.0389x over previous
//
#include <hip/hip_runtime.h>
#include <cmath>

// Problem constants: B=4, L=8192, H=128, P=64
constexpr int Bn = 4;
constexpr int Ln = 8192;
constexpr int Hn = 128;
constexpr int Pn = 64;
constexpr int Kn = 128;         // 2*P interleaved (k = 2p+c)
constexpr int Sc = 64;          // chunk length (rows per block)
constexpr int NC = Ln / Sc;     // 128 chunks per batch
constexpr int NBLK = Bn * NC;   // 512 blocks

typedef float f4 __attribute__((ext_vector_type(4)));
typedef float f32x4 __attribute__((ext_vector_type(4)));
typedef unsigned short us8 __attribute__((ext_vector_type(8)));
typedef unsigned short us4 __attribute__((ext_vector_type(4)));
typedef __bf16 bf16x8 __attribute__((ext_vector_type(8)));

__device__ __forceinline__ unsigned short f2bf(float f) {
  unsigned u = __builtin_bit_cast(unsigned, f);
  u += 0x7fffu + ((u >> 16) & 1u);        // round-to-nearest-even
  return (unsigned short)(u >> 16);
}
__device__ __forceinline__ float bf2f(unsigned short v) {
  return __builtin_bit_cast(float, (unsigned)v << 16);
}

__device__ __forceinline__ f32x4 mfma_bf16(us8 a, us8 b, f32x4 c) {
  return __builtin_amdgcn_mfma_f32_16x16x32_bf16(
      __builtin_bit_cast(bf16x8, a), __builtin_bit_cast(bf16x8, b), c, 0, 0, 0);
}

__device__ __forceinline__ void make_M(float A, float st,
    float& m11, float& m12, float& m21, float& m22) {
  float s2A   = st * st * A;
  float schur = 1.0f / (1.0f + s2A);
  m11 = 1.0f - s2A * schur;
  m12 = -st * A * schur;
  m21 = st * schur;
  m22 = schur;
}

struct M22 { float a, b, c, d; };   // [[a,b],[c,d]]
__device__ __forceinline__ M22 mmul(M22 X, M22 Y) {
  return { X.a * Y.a + X.b * Y.c, X.a * Y.b + X.b * Y.d,
           X.c * Y.a + X.d * Y.c, X.c * Y.b + X.d * Y.d };
}

// W-in-LDS swizzle: row n (256B), byte ^= (n&7)<<4  (read & write use same involution)
__device__ __forceinline__ char* wswz(unsigned short* wlds, int n, int byteInRow) {
  return (char*)wlds + ((n * 256 + byteInRow) ^ ((n & 7) << 4));
}
__device__ __forceinline__ const char* wswz_c(const unsigned short* wlds, int n, int byteInRow) {
  return (const char*)wlds + ((n * 256 + byteInRow) ^ ((n & 7) << 4));
}

// ------------------------------------------------- K1: Wb->LDS + GEMM1(reg) + zero-init scan -> ysl + carry
__global__ __launch_bounds__(256) void k1_kernel(
    const float* __restrict__ u, const float* __restrict__ Br,
    const float* __restrict__ Bi, const float* __restrict__ Ad,
    const float* __restrict__ steps,
    float2* __restrict__ carry, unsigned short* __restrict__ ysl) {
  __shared__ unsigned short usb[Sc * Hn];   // 16 KB: u-tile (swz), later ys_local bf16 (linear)
  __shared__ float bu[Sc * Kn];             // 32 KB: first Wb bf16 (swz), then Bu f32
  unsigned short* wlds = (unsigned short*)bu;
  const int t = threadIdx.x;
  const int b = blockIdx.x >> 7;            // NC = 128
  const int chunk = blockIdx.x & (NC - 1);
  const size_t row0 = (size_t)b * Ln + (size_t)chunk * Sc;

  // stage u tile -> bf16 swizzled LDS
  const f4* __restrict__ u4 = (const f4*)(u + row0 * Hn);
  #pragma unroll
  for (int i = 0; i < 8; ++i) {
    int idx = t + i * 256;
    f4 v = u4[idx];
    int row = idx >> 5, c0 = (idx & 31) * 4;
    us4 pk = {f2bf(v[0]), f2bf(v[1]), f2bf(v[2]), f2bf(v[3])};
    *(us4*)((char*)usb + ((row * 256 + c0 * 2) ^ ((row & 7) << 4))) = pk;
  }

  // stage Wb -> LDS bf16 (swizzled): WbN[n][h] = (n&1?Bi:Br)[n>>1][h]
  #pragma unroll
  for (int i = 0; i < 16; ++i) {
    int idx4 = t + i * 256;                 // 0..4095 us4-groups
    int n = idx4 >> 5, h4 = idx4 & 31;      // h = 4*h4
    const float* __restrict__ src = ((n & 1) ? Bi : Br) + (n >> 1) * Hn + h4 * 4;
    f4 w = *(const f4*)src;
    us4 pk = {f2bf(w[0]), f2bf(w[1]), f2bf(w[2]), f2bf(w[3])};
    *(us4*)wswz(wlds, n, h4 * 8) = pk;
  }
  __syncthreads();

  // GEMM1, all 8 col-tiles accumulated in registers
  const int wave = t >> 6, lane = t & 63;
  const int arow = wave * 16 + (lane & 15);
  const int kg = lane >> 4;                 // h = kk*32 + kg*8 + j

  us8 afr[4];
  #pragma unroll
  for (int kk = 0; kk < 4; ++kk)
    afr[kk] = *(const us8*)((const char*)usb +
        ((arow * 256 + kk * 64 + kg * 16) ^ ((arow & 7) << 4)));

  f32x4 accs[8];
  #pragma unroll
  for (int nt = 0; nt < 8; ++nt) {
    const int n = nt * 16 + (lane & 15);
    f32x4 acc = {0.f, 0.f, 0.f, 0.f};
    #pragma unroll
    for (int kk = 0; kk < 4; ++kk) {
      us8 bfr = *(const us8*)wswz_c(wlds, n, kk * 64 + kg * 16);
      acc = mfma_bf16(afr[kk], bfr, acc);
    }
    accs[nt] = acc;
  }
  __syncthreads();          // all W reads complete before clobbering with Bu

  const int crow = wave * 16 + (lane >> 4) * 4;   // verified m89 C/D mapping
  #pragma unroll
  for (int nt = 0; nt < 8; ++nt) {
    const int ccol = nt * 16 + (lane & 15);
    #pragma unroll
    for (int r = 0; r < 4; ++r)
      bu[(crow + r) * Kn + ccol] = accs[nt][r];
  }
  __syncthreads();

  // local zero-init scan; ys_local(x) -> usb (linear bf16), carry -> global
  if (t < Kn) {
    const int p = t >> 1;
    const float A  = fmaxf(Ad[p], 0.0f);
    const float st = 1.0f / (1.0f + expf(-steps[p]));
    float m11, m12, m21, m22;
    make_M(A, st, m11, m12, m21, m22);
    const float f1 = m11 * st, f2 = m21 * st;
    float z = 0.f, x = 0.f;
    #pragma unroll 8
    for (int s = 0; s < Sc; ++s) {
      float bv = bu[s * Kn + t];
      float zn = fmaf(m11, z, fmaf(m12, x, f1 * bv));
      float xn = fmaf(m21, z, fmaf(m22, x, f2 * bv));
      z = zn; x = xn;
      usb[s * Kn + t] = f2bf(x);
    }
    carry[((size_t)b * NC + chunk) * Kn + t] = make_float2(z, x);
  }
  __syncthreads();

  // ys_local bf16 tile -> global (vectorized, coalesced)
  const us8* src = (const us8*)usb;
  us8* dst = (us8*)(ysl + row0 * Kn);
  #pragma unroll
  for (int i = 0; i < 4; ++i) dst[t + i * 256] = src[t + i * 256];
}

// ------------------------------------------------- K2: wave-parallel carry propagation (proven r8)
__global__ __launch_bounds__(256) void k2_propagate(
    const float* __restrict__ Ad, const float* __restrict__ steps,
    float2* __restrict__ carry) {
  const int wave = threadIdx.x >> 6, lane = threadIdx.x & 63;
  const int series = blockIdx.x * 4 + wave;   // 0..511
  const int sb = series >> 7;
  const int k = series & 127;
  const int p = k >> 1;

  const float A  = fmaxf(Ad[p], 0.0f);
  const float st = 1.0f / (1.0f + expf(-steps[p]));
  float m11, m12, m21, m22;
  make_M(A, st, m11, m12, m21, m22);
  // Mc = M^Sc (Sc=64 -> 6 squarings)
  float ca = m11, cb = m12, cc = m21, cd = m22;
  #pragma unroll
  for (int i = 0; i < 6; ++i) {
    float na = ca * ca + cb * cc;
    float nb = ca * cb + cb * cd;
    float nc = cc * ca + cd * cc;
    float nd = cc * cb + cd * cd;
    ca = na; cb = nb; cc = nc; cd = nd;
  }

  const size_t base = (size_t)sb * NC * Kn + k;
  float2 c0 = carry[base + (size_t)(2 * lane) * Kn];
  float2 c1 = carry[base + (size_t)(2 * lane + 1) * Kn];

  // lane-local fold of chunks {2i, 2i+1}
  float Aa = ca * ca + cb * cc;
  float Ab = ca * cb + cb * cd;
  float Ac = cc * ca + cd * cc;
  float Adl = cc * cb + cd * cd;
  float bz = ca * c0.x + cb * c0.y + c1.x;
  float bx = cc * c0.x + cd * c0.y + c1.y;

  // inclusive shfl-scan of affine maps
  #pragma unroll
  for (int d = 1; d < 64; d <<= 1) {
    float oAa = __shfl_up(Aa, d), oAb = __shfl_up(Ab, d);
    float oAc = __shfl_up(Ac, d), oAd = __shfl_up(Adl, d);
    float obz = __shfl_up(bz, d), obx = __shfl_up(bx, d);
    if (lane >= d) {
      float nbz = Aa * obz + Ab * obx + bz;
      float nbx = Ac * obz + Adl * obx + bx;
      float nAa = Aa * oAa + Ab * oAc;
      float nAb = Aa * oAb + Ab * oAd;
      float nAc = Ac * oAa + Adl * oAc;
      float nAd = Ac * oAb + Adl * oAd;
      Aa = nAa; Ab = nAb; Ac = nAc; Adl = nAd; bz = nbz; bx = nbx;
    }
  }

  // exclusive prefix; init for chunk 2i, then 2i+1 = Mc*init + c0
  float ebz = __shfl_up(bz, 1);
  float ebx = __shfl_up(bx, 1);
  if (lane == 0) { ebz = 0.f; ebx = 0.f; }

  carry[base + (size_t)(2 * lane) * Kn]     = make_float2(ebz, ebx);
  carry[base + (size_t)(2 * lane + 1) * Kn] =
      make_float2(ca * ebz + cb * ebx + c0.x, cc * ebz + cd * ebx + c0.y);
}

// ------------------------------------------------- K3: Wc->LDS + correction + GEMM2(reg) + residual
__global__ __launch_bounds__(256) void k3_kernel(
    const float* __restrict__ u, const float* __restrict__ Cr,
    const float* __restrict__ Ci, const float* __restrict__ Dv,
    const float* __restrict__ Ad, const float* __restrict__ steps,
    const float2* __restrict__ carry, const unsigned short* __restrict__ ysl,
    float* __restrict__ out) {
  __shared__ unsigned short usb[Sc * Kn];   // 16 KB: corrected ys bf16 (swizzled)
  __shared__ float olds[Sc * Kn];           // 32 KB: first Wc bf16 (swz), then GEMM2 output
  unsigned short* wlds = (unsigned short*)olds;
  const int t = threadIdx.x;
  const int b = blockIdx.x >> 7;
  const int chunk = blockIdx.x & (NC - 1);
  const size_t row0 = (size_t)b * Ln + (size_t)chunk * Sc;

  // stage Wc -> LDS bf16 (swizzled): WcH[h][k] = (k&1 ? -Ci : Cr)[h][k>>1]
  #pragma unroll
  for (int i = 0; i < 16; ++i) {
    int idx4 = t + i * 256;                 // 0..4095 us4-groups
    int h = idx4 >> 5, k4 = (idx4 & 31) * 4;
    const float2 cr = *(const float2*)(Cr + h * Pn + (k4 >> 1));
    const float2 ci = *(const float2*)(Ci + h * Pn + (k4 >> 1));
    us4 pk = {f2bf(cr.x), f2bf(-ci.x), f2bf(cr.y), f2bf(-ci.y)};
    *(us4*)wswz(wlds, h, k4 * 2) = pk;
  }

  const int tc = t & 31;        // cols k = 4tc..4tc+3; p = {2tc, 2tc+1}
  const int r0 = t >> 5;        // rows r0, r0+8, ..., r0+56

  // chunk init state per k (fixed per thread)
  const size_t cbase = ((size_t)b * NC + chunk) * Kn;
  float2 iv[4];
  #pragma unroll
  for (int j = 0; j < 4; ++j) iv[j] = carry[cbase + 4 * tc + j];

  // per-p transition matrices and power ladder: row s needs M^(s+1)
  M22 M0, M1;
  {
    int p0 = 2 * tc, p1 = 2 * tc + 1;
    float A0 = fmaxf(Ad[p0], 0.0f), A1 = fmaxf(Ad[p1], 0.0f);
    float s0 = 1.0f / (1.0f + expf(-steps[p0]));
    float s1 = 1.0f / (1.0f + expf(-steps[p1]));
    make_M(A0, s0, M0.a, M0.b, M0.c, M0.d);
    make_M(A1, s1, M1.a, M1.b, M1.c, M1.d);
  }
  M22 M8_0 = mmul(mmul(mmul(M0, M0), mmul(M0, M0)), mmul(mmul(M0, M0), mmul(M0, M0)));
  M22 M8_1 = mmul(mmul(mmul(M1, M1), mmul(M1, M1)), mmul(mmul(M1, M1), mmul(M1, M1)));
  M22 R0 = M0, R1 = M1;                    // M^(r0+1)
  for (int q = 0; q < r0; ++q) { R0 = mmul(R0, M0); R1 = mmul(R1, M1); }

  // corrected ys -> bf16 swizzled A-tile
  const unsigned short* yrow = ysl + row0 * Kn + 4 * tc;
  #pragma unroll
  for (int i = 0; i < 8; ++i) {
    const int row = r0 + 8 * i;
    us4 yv = *(const us4*)(yrow + (size_t)row * Kn);
    float y0 = bf2f(yv[0]) + fmaf(R0.c, iv[0].x, R0.d * iv[0].y);
    float y1 = bf2f(yv[1]) + fmaf(R0.c, iv[1].x, R0.d * iv[1].y);
    float y2 = bf2f(yv[2]) + fmaf(R1.c, iv[2].x, R1.d * iv[2].y);
    float y3 = bf2f(yv[3]) + fmaf(R1.c, iv[3].x, R1.d * iv[3].y);
    us4 pk = {f2bf(y0), f2bf(y1), f2bf(y2), f2bf(y3)};
    *(us4*)((char*)usb + ((row * 256 + tc * 8) ^ ((row & 7) << 4))) = pk;
    R0 = mmul(M8_0, R0); R1 = mmul(M8_1, R1);
  }
  __syncthreads();

  // GEMM2, all 8 col-tiles in registers (B-frags from swizzled LDS Wc)
  const int wave = t >> 6, lane = t & 63;
  const int arow = wave * 16 + (lane & 15);
  const int kg = lane >> 4;

  us8 afr[4];
  #pragma unroll
  for (int kk = 0; kk < 4; ++kk)
    afr[kk] = *(const us8*)((const char*)usb +
        ((arow * 256 + kk * 64 + kg * 16) ^ ((arow & 7) << 4)));

  f32x4 accs[8];
  #pragma unroll
  for (int nt = 0; nt < 8; ++nt) {
    const int n = nt * 16 + (lane & 15);   // h
    f32x4 acc = {0.f, 0.f, 0.f, 0.f};
    #pragma unroll
    for (int kk = 0; kk < 4; ++kk) {
      us8 bfr = *(const us8*)wswz_c(wlds, n, kk * 64 + kg * 16);
      acc = mfma_bf16(afr[kk], bfr, acc);
    }
    accs[nt] = acc;
  }
  __syncthreads();          // all W reads complete before clobbering with output

  const int crow = wave * 16 + (lane >> 4) * 4;
  #pragma unroll
  for (int nt = 0; nt < 8; ++nt) {
    const int ccol = nt * 16 + (lane & 15);
    #pragma unroll
    for (int r = 0; r < 4; ++r)
      olds[(crow + r) * Kn + ccol] = accs[nt][r];
  }
  __syncthreads();

  // residual + coalesced store (r8-proven vectorized epilogue)
  const f4* __restrict__ Dv4 = (const f4*)Dv;
  const f4* __restrict__ u4 = (const f4*)(u + row0 * Hn);
  f4* __restrict__ out4 = (f4*)out;
  #pragma unroll
  for (int i = 0; i < 8; ++i) {
    int idx = t + i * 256;
    int row = idx >> 5, c0 = (idx & 31) * 4;
    f4 acc = *(const f4*)&olds[row * Kn + c0];
    f4 uv = u4[idx];
    f4 dv = Dv4[idx & 31];
    f4 res;
    #pragma unroll
    for (int j = 0; j < 4; ++j) res[j] = fmaf(uv[j], dv[j], acc[j]);
    out4[row0 * (Hn / 4) + idx] = res;
  }
}

extern "C" void kernel_launch(void* const* d_in, const int* in_sizes, int n_in,
                              void* d_out, int out_size, void* d_ws, size_t ws_size,
                              hipStream_t stream) {
  const float* u     = (const float*)d_in[0];
  const float* Ad    = (const float*)d_in[1];
  const float* Br    = (const float*)d_in[2];
  const float* Bi    = (const float*)d_in[3];
  const float* Cr    = (const float*)d_in[4];
  const float* Ci    = (const float*)d_in[5];
  const float* Dv    = (const float*)d_in[6];
  const float* steps = (const float*)d_in[7];
  float* out = (float*)d_out;

  // ws: carry [B*NC*Kn float2 = 512KB] | ysl bf16 [8MB]
  float2* carry = (float2*)d_ws;
  unsigned short* ysl = (unsigned short*)(carry + (size_t)Bn * NC * Kn);

  k1_kernel   <<<NBLK,        256, 0, stream>>>(u, Br, Bi, Ad, steps, carry, ysl);
  k2_propagate<<<Bn * Kn / 4, 256, 0, stream>>>(Ad, steps, carry);
  k3_kernel   <<<NBLK,        256, 0, stream>>>(u, Cr, Ci, Dv, Ad, steps, carry, ysl, out);
}